// Round 8
// baseline (340.617 us; speedup 1.0000x reference)
//
#include <hip/hip_runtime.h>
#include <hip/hip_bf16.h>

// SAGAN self-attention, B=16, C=128, H=W=64. Inputs fp32, output fp32.
// *** DIAGNOSTIC ROUND: convpool + attn_out bodies run REP=3 times so their
// dispatch durations exceed the ~42us fill threshold and appear in the
// rocprof top-5 with full counters. Work is idempotent; rep-top barriers
// protect LDS reuse. Revert REP to 1 next round. ***
// ws layout in ushorts (bf16):
//   U_WN  = 0        : Wn bf16 [96][128] (theta 0..15, phi 16..31, g 32..95)
//   U_WO  = 12288    : Wo bf16 [128][64]
//   U_TH  = 20480    : thetaT bf16 [16 b][4096 s][16 c]
//   U_PHI = 1069056  : phiT   bf16 [16 b][1024 t][16 c]
//   U_G   = 1331200  : g      bf16 [16 b][64 c][1024 t]

#define U_WN  0
#define U_WO  12288
#define U_TH  20480
#define U_PHI 1069056
#define U_G   1331200

#define REP_CONV 3
#define REP_ATTN 3

typedef __attribute__((ext_vector_type(8))) short bf16x8;
typedef __attribute__((ext_vector_type(4))) short s16x4;
typedef __attribute__((ext_vector_type(4))) float f32x4;
typedef __attribute__((ext_vector_type(16))) float f32x16;

__device__ inline unsigned short f2b(float f) {
    union { float f; unsigned u; } v; v.f = f;
    unsigned r = v.u + 0x7FFFu + ((v.u >> 16) & 1u);   // RNE
    return (unsigned short)(r >> 16);
}
__device__ inline float b2f(unsigned short u) {
    union { unsigned u; float f; } v; v.u = ((unsigned)u) << 16; return v.f;
}

__device__ inline unsigned cvtpk_bf16(float lo, float hi) {
    unsigned r;
    asm("s_nop 0\n\tv_cvt_pk_bf16_f32 %0, %1, %2" : "=v"(r) : "v"(lo), "v"(hi));
    return r;
}
__device__ inline void pl32swap(unsigned &a, unsigned &b) {
    asm("s_nop 1\n\tv_permlane32_swap_b32 %0, %1\n\ts_nop 1" : "+v"(a), "+v"(b));
}
__device__ inline void gload_lds16(const unsigned short* g, unsigned short* l) {
    __builtin_amdgcn_global_load_lds(
        (const __attribute__((address_space(1))) unsigned int*)g,
        (__attribute__((address_space(3))) unsigned int*)l, 16, 0, 0);
}

// ---------------- Kernel A: spectral norm, emit bf16 weights ----------------
__global__ __launch_bounds__(256) void sn4(
        const float* __restrict__ w0, const float* __restrict__ w1,
        const float* __restrict__ w2, const float* __restrict__ w3,
        const float* __restrict__ u0, const float* __restrict__ u1,
        const float* __restrict__ u2, const float* __restrict__ u3,
        unsigned short* __restrict__ wsu) {
    int wi = blockIdx.x;
    const float* W; const float* u; unsigned short* dst; int on, in_;
    if      (wi == 0) { W = w0; u = u0; dst = wsu;          on = 16;  in_ = 128; }
    else if (wi == 1) { W = w1; u = u1; dst = wsu + 2048;   on = 16;  in_ = 128; }
    else if (wi == 2) { W = w2; u = u2; dst = wsu + 4096;   on = 64;  in_ = 128; }
    else              { W = w3; u = u3; dst = wsu + 12288;  on = 128; in_ = 64;  }
    __shared__ float Wl[8320];    // [on][in_+1], max(128*65, 64*129) = 8320
    __shared__ float ul[128];
    __shared__ float v[128];
    __shared__ float red[256];
    __shared__ float s_inv;
    int tid = threadIdx.x;
    int n = on * in_;
    int stride = in_ + 1;
    int shift = (in_ == 128) ? 7 : 6;
    int mask = in_ - 1;
    for (int i = tid; i < n; i += 256) {
        int o = i >> shift, j = i & mask;
        Wl[o * stride + j] = W[i];
    }
    if (tid < on) ul[tid] = u[tid];
    __syncthreads();
    float vi = 0.f;
    if (tid < in_) {
        for (int o = 0; o < on; ++o) vi += ul[o] * Wl[o * stride + tid];
    }
    red[tid] = (tid < in_) ? vi * vi : 0.f;
    __syncthreads();
    for (int st = 128; st > 0; st >>= 1) {
        if (tid < st) red[tid] += red[tid + st];
        __syncthreads();
    }
    float inv_nv = 1.0f / fmaxf(sqrtf(red[0]), 1e-12f);
    __syncthreads();
    if (tid < in_) v[tid] = vi * inv_nv;
    __syncthreads();
    float ui = 0.f;
    if (tid < on) {
        for (int i = 0; i < in_; ++i) ui += v[i] * Wl[tid * stride + i];
    }
    red[tid] = (tid < on) ? ui * ui : 0.f;
    __syncthreads();
    for (int st = 128; st > 0; st >>= 1) {
        if (tid < st) red[tid] += red[tid + st];
        __syncthreads();
    }
    if (tid == 0) {
        float nsq = red[0];
        float sv = nsq / fmaxf(sqrtf(nsq), 1e-12f);
        s_inv = 1.0f / sv;
    }
    __syncthreads();
    float inv = s_inv;
    for (int e = tid; e < n; e += 256) {
        int o = e >> shift, j = e & mask;
        dst[e] = f2b(Wl[o * stride + j] * inv);
    }
}

// ------- Kernel B: MFMA conv + 2x2 maxpool (r7 body, REP_CONV reps) ---------
__global__ __launch_bounds__(512, 4) void convpool_mfma(
        const float* __restrict__ x, const unsigned short* __restrict__ wn,
        unsigned short* __restrict__ thetaT, unsigned short* __restrict__ phiT,
        unsigned short* __restrict__ gT) {
    __shared__ unsigned short xT[128 * 136];   // [px][c], stride 136
    __shared__ unsigned short wnl[96 * 136];   // [oc][c], stride 136; reused as poolbuf
    int tid = threadIdx.x;
    int bb = blockIdx.x >> 5, tile = blockIdx.x & 31;
    int px0 = tile << 7;
    for (int rep = 0; rep < REP_CONV; ++rep) {
    __syncthreads();   // protect poolbuf reads of previous rep
    for (int i = tid; i < 1536; i += 512) {
        int r = i >> 4, c8 = (i & 15) * 8;
        *(bf16x8*)&wnl[r * 136 + c8] = *(const bf16x8*)&wn[r * 128 + c8];
    }
    const float4* x4 = (const float4*)x;
    {
        int p4 = tid & 31, cg = (tid >> 5) * 4;    // cg 0..60
        for (int k = 0; k < 2; ++k) {
            int cb = k * 64 + cg;
            float4 v0 = x4[(bb * 128 + cb + 0) * 1024 + tile * 32 + p4];
            float4 v1 = x4[(bb * 128 + cb + 1) * 1024 + tile * 32 + p4];
            float4 v2 = x4[(bb * 128 + cb + 2) * 1024 + tile * 32 + p4];
            float4 v3 = x4[(bb * 128 + cb + 3) * 1024 + tile * 32 + p4];
            float a0[4] = {v0.x, v0.y, v0.z, v0.w};
            float a1[4] = {v1.x, v1.y, v1.z, v1.w};
            float a2[4] = {v2.x, v2.y, v2.z, v2.w};
            float a3[4] = {v3.x, v3.y, v3.z, v3.w};
#pragma unroll
            for (int j = 0; j < 4; ++j) {
                union { unsigned w[2]; s16x4 v; } pk;
                pk.w[0] = cvtpk_bf16(a0[j], a1[j]);   // channels cb, cb+1
                pk.w[1] = cvtpk_bf16(a2[j], a3[j]);   // channels cb+2, cb+3
                *(s16x4*)&xT[(p4 * 4 + j) * 136 + cb] = pk.v;
            }
        }
    }
    __syncthreads();
    int lane = tid & 63, wv = tid >> 6;        // wv 0..7
    int q = lane >> 4, l = lane & 15;
    int pxw = wv * 16;
    f32x4 acc[6];
    const f32x4 z4 = {0.f, 0.f, 0.f, 0.f};
#pragma unroll
    for (int nt = 0; nt < 6; ++nt) acc[nt] = z4;
#pragma unroll
    for (int kk = 0; kk < 4; ++kk) {
        bf16x8 a0 = *(const bf16x8*)&xT[(pxw + l) * 136 + kk * 32 + q * 8];
#pragma unroll
        for (int nt = 0; nt < 6; ++nt) {
            bf16x8 bw = *(const bf16x8*)&wnl[(nt * 16 + l) * 136 + kk * 32 + q * 8];
            acc[nt] = __builtin_amdgcn_mfma_f32_16x16x32_bf16(a0, bw, acc[nt], 0, 0, 0);
        }
    }
    // theta (nt=0): thetaT[s][c], c=l
#pragma unroll
    for (int r = 0; r < 4; ++r) {
        int s = px0 + pxw + q * 4 + r;
        thetaT[(bb * 4096 + s) * 16 + l] = f2b(acc[0][r]);
    }
    __syncthreads();   // all waves done reading wnl
    unsigned short* poolbuf = wnl;   // [80 ch][px] stride 132
#pragma unroll
    for (int nt = 1; nt < 6; ++nt) {
        int ch = nt * 16 + l - 16;
#pragma unroll
        for (int r = 0; r < 4; ++r) {
            poolbuf[ch * 132 + pxw + q * 4 + r] = f2b(acc[nt][r]);
        }
    }
    __syncthreads();
    for (int i = tid; i < 2560; i += 512) {
        int tcol = i & 31, ch = i >> 5;
        int base = ch * 132 + tcol * 2;
        float m0 = fmaxf(b2f(poolbuf[base]), b2f(poolbuf[base + 1]));
        float m1 = fmaxf(b2f(poolbuf[base + 64]), b2f(poolbuf[base + 65]));
        float m = fmaxf(m0, m1);
        int t = tile * 32 + tcol;
        if (ch < 16) phiT[(bb * 1024 + t) * 16 + ch] = f2b(m);
        else         gT[(bb * 64 + ch - 16) * 1024 + t] = f2b(m);
    }
    }   // rep
}

// ------- Kernel C: fused attention + output conv + residual (r7 body) -------
__global__ __launch_bounds__(256, 4) void attn_out(
        const unsigned short* __restrict__ thetaT,
        const unsigned short* __restrict__ phiT,
        const unsigned short* __restrict__ gT,
        const unsigned short* __restrict__ wo,
        const float* __restrict__ x, const float* __restrict__ gam,
        float* __restrict__ out) {
    __shared__ unsigned short gl[2][2][4096];  // [dbuf][t-half][64c x 64t swz] 32KB
    __shared__ float ldsD[2][2][32];
    float* ldsOf = (float*)&gl[0][0][0];       // combine view (post-loop reuse)
    int tid = threadIdx.x;
    // XCD-chunked bijective swizzle (1024 = 8 XCD x 128 chunks)
    int kblk = blockIdx.x;
    int vblk = (kblk & 7) * 128 + (kblk >> 3);
    int bb = vblk >> 6, st = vblk & 63;
    int s0 = st << 6;
    int lane = tid & 63, wv = tid >> 6;
    int sg = wv & 1, sp = wv >> 1;
    int sl = lane & 31, hi = lane >> 5;
    int srow = bb * 4096 + s0 + sg * 32 + sl;      // this lane's s (global)
    const unsigned short* phiB = phiT + bb * 16384;    // [1024][16]
    const unsigned short* gB   = gT + bb * 65536;      // [64][1024]
    int tbase = sp << 9;                               // 0 or 512
    // DMA staging geometry: wave wv stages t-half h = wv>>1, row slab
    // rb = (wv&1)*32. Lane: row rb+k*8+(lane>>3), slot j = lane&7;
    // source t-slot = j ^ ((lane>>3)&7) (involution).
    int h = wv >> 1;
    int rb = (wv & 1) * 32;
    int cl = lane >> 3, js = lane & 7;
    const unsigned short* gsl = gB + (rb + cl) * 1024 + h * 512 + ((js ^ cl) * 8);
    int rsw = (sl & 7) << 3;

    for (int rep = 0; rep < REP_ATTN; ++rep) {
    __syncthreads();   // protect previous rep's epilogue LDS reads
    // prologue: stage chunk 0 into buf 0
#pragma unroll
    for (int k = 0; k < 4; ++k)
        gload_lds16(gsl + k * 8192, &gl[0][h][(rb + k * 8) * 64]);

    // theta B-frag: B[k=c=hi*8+j][col=s=sl], loop-invariant
    bf16x8 bth = *(const bf16x8*)&thetaT[srow * 16 + hi * 8];

    f32x16 z16;
#pragma unroll
    for (int i = 0; i < 16; ++i) z16[i] = 0.f;
    f32x16 acc0 = z16, acc1 = z16;     // O rows c 0..31 / 32..63, col s=sl
    float lp4[4] = {0.f, 0.f, 0.f, 0.f};

    // phi A-frag 1-deep pipeline: A[row=t][k=c=hi*8+j]
    bf16x8 ph0 = *(const bf16x8*)&phiB[(tbase + sl) * 16 + hi * 8];
    bf16x8 ph1 = *(const bf16x8*)&phiB[(tbase + 32 + sl) * 16 + hi * 8];
    __syncthreads();   // chunk 0 DMA drained by barrier's vmcnt(0)

    for (int tc = 0; tc < 8; ++tc) {
        int buf = tc & 1;
        if (tc < 7) {
#pragma unroll
            for (int k = 0; k < 4; ++k)
                gload_lds16(gsl + k * 8192 + (tc + 1) * 64,
                            &gl[buf ^ 1][h][(rb + k * 8) * 64]);
        }
        f32x16 sa = __builtin_amdgcn_mfma_f32_32x32x16_bf16(ph0, bth, z16, 0, 0, 0);
        unsigned u0[8], u1[8];
#pragma unroll
        for (int i = 0; i < 8; ++i) {
            float e0 = __expf(sa[2 * i]);
            float e1 = __expf(sa[2 * i + 1]);
            lp4[0] += e0; lp4[1] += e1;
            u0[i] = cvtpk_bf16(e0, e1);
        }
        __builtin_amdgcn_sched_barrier(0);
        f32x16 sb = __builtin_amdgcn_mfma_f32_32x32x16_bf16(ph1, bth, z16, 0, 0, 0);
        pl32swap(u0[0], u0[2]); pl32swap(u0[1], u0[3]);
        pl32swap(u0[4], u0[6]); pl32swap(u0[5], u0[7]);
        const unsigned short* glr = &gl[buf][sp][0];
        __builtin_amdgcn_s_setprio(1);
        {
            int co = (0 * 16 + hi * 8) ^ rsw;
            bf16x8 gf0 = *(const bf16x8*)&glr[sl * 64 + co];
            bf16x8 gf1 = *(const bf16x8*)&glr[(32 + sl) * 64 + co];
            union { unsigned w[4]; bf16x8 v; } pf = {{u0[0], u0[1], u0[2], u0[3]}};
            acc0 = __builtin_amdgcn_mfma_f32_32x32x16_bf16(gf0, pf.v, acc0, 0, 0, 0);
            acc1 = __builtin_amdgcn_mfma_f32_32x32x16_bf16(gf1, pf.v, acc1, 0, 0, 0);
        }
        {
            int co = (1 * 16 + hi * 8) ^ rsw;
            bf16x8 gf0 = *(const bf16x8*)&glr[sl * 64 + co];
            bf16x8 gf1 = *(const bf16x8*)&glr[(32 + sl) * 64 + co];
            union { unsigned w[4]; bf16x8 v; } pf = {{u0[4], u0[5], u0[6], u0[7]}};
            acc0 = __builtin_amdgcn_mfma_f32_32x32x16_bf16(gf0, pf.v, acc0, 0, 0, 0);
            acc1 = __builtin_amdgcn_mfma_f32_32x32x16_bf16(gf1, pf.v, acc1, 0, 0, 0);
        }
        __builtin_amdgcn_s_setprio(0);
        int t0n = tbase + (((tc + 1) & 7) << 6);
        ph0 = *(const bf16x8*)&phiB[(t0n + sl) * 16 + hi * 8];
        ph1 = *(const bf16x8*)&phiB[(t0n + 32 + sl) * 16 + hi * 8];
#pragma unroll
        for (int i = 0; i < 8; ++i) {
            float e2 = __expf(sb[2 * i]);
            float e3 = __expf(sb[2 * i + 1]);
            lp4[2] += e2; lp4[3] += e3;
            u1[i] = cvtpk_bf16(e2, e3);
        }
        pl32swap(u1[0], u1[2]); pl32swap(u1[1], u1[3]);
        pl32swap(u1[4], u1[6]); pl32swap(u1[5], u1[7]);
        __builtin_amdgcn_s_setprio(1);
        {
            int co = (2 * 16 + hi * 8) ^ rsw;
            bf16x8 gf0 = *(const bf16x8*)&glr[sl * 64 + co];
            bf16x8 gf1 = *(const bf16x8*)&glr[(32 + sl) * 64 + co];
            union { unsigned w[4]; bf16x8 v; } pf = {{u1[0], u1[1], u1[2], u1[3]}};
            acc0 = __builtin_amdgcn_mfma_f32_32x32x16_bf16(gf0, pf.v, acc0, 0, 0, 0);
            acc1 = __builtin_amdgcn_mfma_f32_32x32x16_bf16(gf1, pf.v, acc1, 0, 0, 0);
        }
        {
            int co = (3 * 16 + hi * 8) ^ rsw;
            bf16x8 gf0 = *(const bf16x8*)&glr[sl * 64 + co];
            bf16x8 gf1 = *(const bf16x8*)&glr[(32 + sl) * 64 + co];
            union { unsigned w[4]; bf16x8 v; } pf = {{u1[4], u1[5], u1[6], u1[7]}};
            acc0 = __builtin_amdgcn_mfma_f32_32x32x16_bf16(gf0, pf.v, acc0, 0, 0, 0);
            acc1 = __builtin_amdgcn_mfma_f32_32x32x16_bf16(gf1, pf.v, acc1, 0, 0, 0);
        }
        __builtin_amdgcn_s_setprio(0);
        if (tc < 7) __syncthreads();
    }
    __syncthreads();   // all PV reads done before gl is reused as ldsOf

    float tot = (lp4[0] + lp4[1]) + (lp4[2] + lp4[3]);
    tot += __shfl_xor(tot, 32);
#pragma unroll
    for (int i = 0; i < 16; ++i) {
        int c = (i & 3) + 8 * (i >> 2) + 4 * hi;
        ldsOf[(sg * 2 + sp) * 2048 + c * 32 + sl] = acc0[i];
        ldsOf[(sg * 2 + sp) * 2048 + (32 + c) * 32 + sl] = acc1[i];
    }
    if (hi == 0) ldsD[sg][sp][sl] = tot;
    bf16x8 aw[2][4];
#pragma unroll
    for (int mt = 0; mt < 2; ++mt)
#pragma unroll
        for (int ch = 0; ch < 4; ++ch)
            aw[mt][ch] = *(const bf16x8*)&wo[(sp * 64 + mt * 32 + sl) * 64 + ch * 16 + hi * 8];
    __syncthreads();
    int osp = sp ^ 1;
    tot += ldsD[sg][osp][sl];
    float inv = 1.0f / tot;
#pragma unroll
    for (int i = 0; i < 16; ++i) {
        int c = (i & 3) + 8 * (i >> 2) + 4 * hi;
        acc0[i] += ldsOf[(sg * 2 + osp) * 2048 + c * 32 + sl];
        acc1[i] += ldsOf[(sg * 2 + osp) * 2048 + (32 + c) * 32 + sl];
    }
    unsigned o0[8], o1[8];
#pragma unroll
    for (int i = 0; i < 8; ++i) {
        o0[i] = cvtpk_bf16(acc0[2 * i] * inv, acc0[2 * i + 1] * inv);
        o1[i] = cvtpk_bf16(acc1[2 * i] * inv, acc1[2 * i + 1] * inv);
    }
    pl32swap(o0[0], o0[2]); pl32swap(o0[1], o0[3]);
    pl32swap(o0[4], o0[6]); pl32swap(o0[5], o0[7]);
    pl32swap(o1[0], o1[2]); pl32swap(o1[1], o1[3]);
    pl32swap(o1[4], o1[6]); pl32swap(o1[5], o1[7]);
    bf16x8 bfr[4];
    {
        union { unsigned w[4]; bf16x8 v; } t;
        t.w[0] = o0[0]; t.w[1] = o0[1]; t.w[2] = o0[2]; t.w[3] = o0[3]; bfr[0] = t.v;
        t.w[0] = o0[4]; t.w[1] = o0[5]; t.w[2] = o0[6]; t.w[3] = o0[7]; bfr[1] = t.v;
        t.w[0] = o1[0]; t.w[1] = o1[1]; t.w[2] = o1[2]; t.w[3] = o1[3]; bfr[2] = t.v;
        t.w[0] = o1[4]; t.w[1] = o1[5]; t.w[2] = o1[6]; t.w[3] = o1[7]; bfr[3] = t.v;
    }
    f32x16 d0 = z16, d1 = z16;
#pragma unroll
    for (int ch = 0; ch < 4; ++ch) {
        d0 = __builtin_amdgcn_mfma_f32_32x32x16_bf16(aw[0][ch], bfr[ch], d0, 0, 0, 0);
        d1 = __builtin_amdgcn_mfma_f32_32x32x16_bf16(aw[1][ch], bfr[ch], d1, 0, 0, 0);
    }
    float gm = gam[0];
    int scol = s0 + sg * 32 + sl;
#pragma unroll
    for (int i = 0; i < 16; ++i) {
        int r = (i & 3) + 8 * (i >> 2) + 4 * hi;
        int a0 = (bb * 128 + sp * 64 + r) * 4096 + scol;
        int a1 = (bb * 128 + sp * 64 + 32 + r) * 4096 + scol;
        out[a0] = gm * d0[i] + x[a0];
        out[a1] = gm * d1[i] + x[a1];
    }
    }   // rep
}

extern "C" void kernel_launch(void* const* d_in, const int* in_sizes, int n_in,
                              void* d_out, int out_size, void* d_ws, size_t ws_size,
                              hipStream_t stream) {
    const float* x  = (const float*)d_in[0];
    const float* wt = (const float*)d_in[1];
    const float* wp = (const float*)d_in[2];
    const float* wg = (const float*)d_in[3];
    const float* wo = (const float*)d_in[4];
    const float* ut = (const float*)d_in[5];
    const float* up = (const float*)d_in[6];
    const float* ug = (const float*)d_in[7];
    const float* uo = (const float*)d_in[8];
    const float* gm = (const float*)d_in[9];
    unsigned short* wsu = (unsigned short*)d_ws;
    float* out = (float*)d_out;

    sn4<<<4, 256, 0, stream>>>(wt, wp, wg, wo, ut, up, ug, uo, wsu);
    convpool_mfma<<<512, 512, 0, stream>>>(x, wsu + U_WN,
                                           wsu + U_TH, wsu + U_PHI, wsu + U_G);
    attn_out<<<1024, 256, 0, stream>>>(wsu + U_TH, wsu + U_PHI, wsu + U_G,
                                       wsu + U_WO, x, gm, out);
}

// Round 9
// 130.188 us; speedup vs baseline: 2.6164x; 2.6164x over previous
//
#include <hip/hip_runtime.h>
#include <hip/hip_bf16.h>

// SAGAN self-attention, B=16, C=128, H=W=64. Inputs fp32, output fp32.
// ws layout in ushorts (bf16):
//   U_WN  = 0        : Wn bf16 [96][128] (theta 0..15, phi 16..31, g 32..95)
//   U_WO  = 12288    : Wo bf16 [128][64]
//   U_TH  = 20480    : thetaT bf16 [16 b][4096 s][16 c]
//   U_PHI = 1069056  : phiT   bf16 [16 b][1024 t][16 c]
//   U_G   = 1331200  : g      bf16 [16 b][64 c][1024 t]

#define U_WN  0
#define U_WO  12288
#define U_TH  20480
#define U_PHI 1069056
#define U_G   1331200

typedef __attribute__((ext_vector_type(8))) short bf16x8;
typedef __attribute__((ext_vector_type(4))) short s16x4;
typedef __attribute__((ext_vector_type(4))) float f32x4;
typedef __attribute__((ext_vector_type(16))) float f32x16;

__device__ inline unsigned short f2b(float f) {
    union { float f; unsigned u; } v; v.f = f;
    unsigned r = v.u + 0x7FFFu + ((v.u >> 16) & 1u);   // RNE
    return (unsigned short)(r >> 16);
}
__device__ inline float b2f(unsigned short u) {
    union { unsigned u; float f; } v; v.u = ((unsigned)u) << 16; return v.f;
}

__device__ inline unsigned cvtpk_bf16(float lo, float hi) {
    unsigned r;
    asm("s_nop 0\n\tv_cvt_pk_bf16_f32 %0, %1, %2" : "=v"(r) : "v"(lo), "v"(hi));
    return r;
}
__device__ inline void pl32swap(unsigned &a, unsigned &b) {
    asm("s_nop 1\n\tv_permlane32_swap_b32 %0, %1\n\ts_nop 1" : "+v"(a), "+v"(b));
}
__device__ inline void gload_lds16(const unsigned short* g, unsigned short* l) {
    __builtin_amdgcn_global_load_lds(
        (const __attribute__((address_space(1))) unsigned int*)g,
        (__attribute__((address_space(3))) unsigned int*)l, 16, 0, 0);
}

// ---------------- Kernel A: spectral norm, emit bf16 weights ----------------
__global__ __launch_bounds__(256) void sn4(
        const float* __restrict__ w0, const float* __restrict__ w1,
        const float* __restrict__ w2, const float* __restrict__ w3,
        const float* __restrict__ u0, const float* __restrict__ u1,
        const float* __restrict__ u2, const float* __restrict__ u3,
        unsigned short* __restrict__ wsu) {
    int wi = blockIdx.x;
    const float* W; const float* u; unsigned short* dst; int on, in_;
    if      (wi == 0) { W = w0; u = u0; dst = wsu;          on = 16;  in_ = 128; }
    else if (wi == 1) { W = w1; u = u1; dst = wsu + 2048;   on = 16;  in_ = 128; }
    else if (wi == 2) { W = w2; u = u2; dst = wsu + 4096;   on = 64;  in_ = 128; }
    else              { W = w3; u = u3; dst = wsu + 12288;  on = 128; in_ = 64;  }
    __shared__ float Wl[8320];    // [on][in_+1], max(128*65, 64*129) = 8320
    __shared__ float ul[128];
    __shared__ float v[128];
    __shared__ float red[256];
    __shared__ float s_inv;
    int tid = threadIdx.x;
    int n = on * in_;
    int stride = in_ + 1;
    int shift = (in_ == 128) ? 7 : 6;
    int mask = in_ - 1;
    for (int i = tid; i < n; i += 256) {
        int o = i >> shift, j = i & mask;
        Wl[o * stride + j] = W[i];
    }
    if (tid < on) ul[tid] = u[tid];
    __syncthreads();
    float vi = 0.f;
    if (tid < in_) {
        for (int o = 0; o < on; ++o) vi += ul[o] * Wl[o * stride + tid];
    }
    red[tid] = (tid < in_) ? vi * vi : 0.f;
    __syncthreads();
    for (int st = 128; st > 0; st >>= 1) {
        if (tid < st) red[tid] += red[tid + st];
        __syncthreads();
    }
    float inv_nv = 1.0f / fmaxf(sqrtf(red[0]), 1e-12f);
    __syncthreads();
    if (tid < in_) v[tid] = vi * inv_nv;
    __syncthreads();
    float ui = 0.f;
    if (tid < on) {
        for (int i = 0; i < in_; ++i) ui += v[i] * Wl[tid * stride + i];
    }
    red[tid] = (tid < on) ? ui * ui : 0.f;
    __syncthreads();
    for (int st = 128; st > 0; st >>= 1) {
        if (tid < st) red[tid] += red[tid + st];
        __syncthreads();
    }
    if (tid == 0) {
        float nsq = red[0];
        float sv = nsq / fmaxf(sqrtf(nsq), 1e-12f);
        s_inv = 1.0f / sv;
    }
    __syncthreads();
    float inv = s_inv;
    for (int e = tid; e < n; e += 256) {
        int o = e >> shift, j = e & mask;
        dst[e] = f2b(Wl[o * stride + j] * inv);
    }
}

// ------- Kernel B: MFMA conv + 2x2 maxpool (round-7 body) -------------------
__global__ __launch_bounds__(512, 4) void convpool_mfma(
        const float* __restrict__ x, const unsigned short* __restrict__ wn,
        unsigned short* __restrict__ thetaT, unsigned short* __restrict__ phiT,
        unsigned short* __restrict__ gT) {
    __shared__ unsigned short xT[128 * 136];   // [px][c], stride 136
    __shared__ unsigned short wnl[96 * 136];   // [oc][c], stride 136; reused as poolbuf
    int tid = threadIdx.x;
    int bb = blockIdx.x >> 5, tile = blockIdx.x & 31;
    int px0 = tile << 7;
    for (int i = tid; i < 1536; i += 512) {
        int r = i >> 4, c8 = (i & 15) * 8;
        *(bf16x8*)&wnl[r * 136 + c8] = *(const bf16x8*)&wn[r * 128 + c8];
    }
    const float4* x4 = (const float4*)x;
    {
        int p4 = tid & 31, cg = (tid >> 5) * 4;    // cg 0..60
        for (int k = 0; k < 2; ++k) {
            int cb = k * 64 + cg;
            float4 v0 = x4[(bb * 128 + cb + 0) * 1024 + tile * 32 + p4];
            float4 v1 = x4[(bb * 128 + cb + 1) * 1024 + tile * 32 + p4];
            float4 v2 = x4[(bb * 128 + cb + 2) * 1024 + tile * 32 + p4];
            float4 v3 = x4[(bb * 128 + cb + 3) * 1024 + tile * 32 + p4];
            float a0[4] = {v0.x, v0.y, v0.z, v0.w};
            float a1[4] = {v1.x, v1.y, v1.z, v1.w};
            float a2[4] = {v2.x, v2.y, v2.z, v2.w};
            float a3[4] = {v3.x, v3.y, v3.z, v3.w};
#pragma unroll
            for (int j = 0; j < 4; ++j) {
                union { unsigned w[2]; s16x4 v; } pk;
                pk.w[0] = cvtpk_bf16(a0[j], a1[j]);   // channels cb, cb+1
                pk.w[1] = cvtpk_bf16(a2[j], a3[j]);   // channels cb+2, cb+3
                *(s16x4*)&xT[(p4 * 4 + j) * 136 + cb] = pk.v;
            }
        }
    }
    __syncthreads();
    int lane = tid & 63, wv = tid >> 6;        // wv 0..7
    int q = lane >> 4, l = lane & 15;
    int pxw = wv * 16;
    f32x4 acc[6];
    const f32x4 z4 = {0.f, 0.f, 0.f, 0.f};
#pragma unroll
    for (int nt = 0; nt < 6; ++nt) acc[nt] = z4;
#pragma unroll
    for (int kk = 0; kk < 4; ++kk) {
        bf16x8 a0 = *(const bf16x8*)&xT[(pxw + l) * 136 + kk * 32 + q * 8];
#pragma unroll
        for (int nt = 0; nt < 6; ++nt) {
            bf16x8 bw = *(const bf16x8*)&wnl[(nt * 16 + l) * 136 + kk * 32 + q * 8];
            acc[nt] = __builtin_amdgcn_mfma_f32_16x16x32_bf16(a0, bw, acc[nt], 0, 0, 0);
        }
    }
    // theta (nt=0): thetaT[s][c], c=l
#pragma unroll
    for (int r = 0; r < 4; ++r) {
        int s = px0 + pxw + q * 4 + r;
        thetaT[(bb * 4096 + s) * 16 + l] = f2b(acc[0][r]);
    }
    __syncthreads();   // all waves done reading wnl
    unsigned short* poolbuf = wnl;   // [80 ch][px] stride 132
#pragma unroll
    for (int nt = 1; nt < 6; ++nt) {
        int ch = nt * 16 + l - 16;
#pragma unroll
        for (int r = 0; r < 4; ++r) {
            poolbuf[ch * 132 + pxw + q * 4 + r] = f2b(acc[nt][r]);
        }
    }
    __syncthreads();
    for (int i = tid; i < 2560; i += 512) {
        int tcol = i & 31, ch = i >> 5;
        int base = ch * 132 + tcol * 2;
        float m0 = fmaxf(b2f(poolbuf[base]), b2f(poolbuf[base + 1]));
        float m1 = fmaxf(b2f(poolbuf[base + 64]), b2f(poolbuf[base + 65]));
        float m = fmaxf(m0, m1);
        int t = tile * 32 + tcol;
        if (ch < 16) phiT[(bb * 1024 + t) * 16 + ch] = f2b(m);
        else         gT[(bb * 64 + ch - 16) * 1024 + t] = f2b(m);
    }
}

// ------- Kernel C: fused attention + output conv + residual -----------------
// Round-9 changes vs round 7 (single-variable: loop sync structure):
//  * counted-vmcnt raw barrier (T4): per-iter vmem sequence is exactly
//    {4 DMA, 2 phi}. vmcnt(2) before s_barrier forces the (older) 4 DMA
//    complete while the 2 phi prefetches stay in flight across the barrier
//    -- removes the vmcnt(0) lockstep drain of __syncthreads.
//  * non-temporal x loads / out stores in the epilogue (keep phi/g/theta
//    L2-resident, avoid RFO).
__global__ __launch_bounds__(256, 4) void attn_out(
        const unsigned short* __restrict__ thetaT,
        const unsigned short* __restrict__ phiT,
        const unsigned short* __restrict__ gT,
        const unsigned short* __restrict__ wo,
        const float* __restrict__ x, const float* __restrict__ gam,
        float* __restrict__ out) {
    __shared__ unsigned short gl[2][2][4096];  // [dbuf][t-half][64c x 64t swz] 32KB
    __shared__ float ldsD[2][2][32];
    float* ldsOf = (float*)&gl[0][0][0];       // combine view (post-loop reuse)
    int tid = threadIdx.x;
    // XCD-chunked bijective swizzle (1024 = 8 XCD x 128 chunks)
    int kblk = blockIdx.x;
    int vblk = (kblk & 7) * 128 + (kblk >> 3);
    int bb = vblk >> 6, st = vblk & 63;
    int s0 = st << 6;
    int lane = tid & 63, wv = tid >> 6;
    int sg = wv & 1, sp = wv >> 1;
    int sl = lane & 31, hi = lane >> 5;
    int srow = bb * 4096 + s0 + sg * 32 + sl;      // this lane's s (global)
    const unsigned short* phiB = phiT + bb * 16384;    // [1024][16]
    const unsigned short* gB   = gT + bb * 65536;      // [64][1024]
    int tbase = sp << 9;                               // 0 or 512

    // DMA staging geometry: wave wv stages t-half h = wv>>1, row slab
    // rb = (wv&1)*32. Lane: row rb+k*8+(lane>>3), slot j = lane&7;
    // source t-slot = j ^ ((lane>>3)&7) (involution).
    int h = wv >> 1;
    int rb = (wv & 1) * 32;
    int cl = lane >> 3, js = lane & 7;
    const unsigned short* gsl = gB + (rb + cl) * 1024 + h * 512 + ((js ^ cl) * 8);
    // prologue: stage chunk 0 into buf 0
#pragma unroll
    for (int k = 0; k < 4; ++k)
        gload_lds16(gsl + k * 8192, &gl[0][h][(rb + k * 8) * 64]);

    // theta B-frag: B[k=c=hi*8+j][col=s=sl], loop-invariant
    bf16x8 bth = *(const bf16x8*)&thetaT[srow * 16 + hi * 8];

    f32x16 z16;
#pragma unroll
    for (int i = 0; i < 16; ++i) z16[i] = 0.f;
    f32x16 acc0 = z16, acc1 = z16;     // O rows c 0..31 / 32..63, col s=sl
    float lp4[4] = {0.f, 0.f, 0.f, 0.f};

    // phi A-frag 1-deep pipeline: A[row=t][k=c=hi*8+j]
    bf16x8 ph0 = *(const bf16x8*)&phiB[(tbase + sl) * 16 + hi * 8];
    bf16x8 ph1 = *(const bf16x8*)&phiB[(tbase + 32 + sl) * 16 + hi * 8];
    __syncthreads();   // chunk 0 DMA drained (full vmcnt(0), one-time)

    int rsw = (sl & 7) << 3;
    for (int tc = 0; tc < 8; ++tc) {
        int buf = tc & 1;
        // issue next-chunk DMA early; full compute phase covers the latency
        if (tc < 7) {
#pragma unroll
            for (int k = 0; k < 4; ++k)
                gload_lds16(gsl + k * 8192 + (tc + 1) * 64,
                            &gl[buf ^ 1][h][(rb + k * 8) * 64]);
        }
        // S^T tile 0: t-block t0+0..31
        f32x16 sa = __builtin_amdgcn_mfma_f32_32x32x16_bf16(ph0, bth, z16, 0, 0, 0);
        unsigned u0[8], u1[8];
#pragma unroll
        for (int i = 0; i < 8; ++i) {
            float e0 = __expf(sa[2 * i]);
            float e1 = __expf(sa[2 * i + 1]);
            lp4[0] += e0; lp4[1] += e1;
            u0[i] = cvtpk_bf16(e0, e1);
        }
        __builtin_amdgcn_sched_barrier(0);
        f32x16 sb = __builtin_amdgcn_mfma_f32_32x32x16_bf16(ph1, bth, z16, 0, 0, 0);
        pl32swap(u0[0], u0[2]); pl32swap(u0[1], u0[3]);
        pl32swap(u0[4], u0[6]); pl32swap(u0[5], u0[7]);
        const unsigned short* glr = &gl[buf][sp][0];
        __builtin_amdgcn_s_setprio(1);
        {
            int co = (0 * 16 + hi * 8) ^ rsw;
            bf16x8 gf0 = *(const bf16x8*)&glr[sl * 64 + co];
            bf16x8 gf1 = *(const bf16x8*)&glr[(32 + sl) * 64 + co];
            union { unsigned w[4]; bf16x8 v; } pf = {{u0[0], u0[1], u0[2], u0[3]}};
            acc0 = __builtin_amdgcn_mfma_f32_32x32x16_bf16(gf0, pf.v, acc0, 0, 0, 0);
            acc1 = __builtin_amdgcn_mfma_f32_32x32x16_bf16(gf1, pf.v, acc1, 0, 0, 0);
        }
        {
            int co = (1 * 16 + hi * 8) ^ rsw;
            bf16x8 gf0 = *(const bf16x8*)&glr[sl * 64 + co];
            bf16x8 gf1 = *(const bf16x8*)&glr[(32 + sl) * 64 + co];
            union { unsigned w[4]; bf16x8 v; } pf = {{u0[4], u0[5], u0[6], u0[7]}};
            acc0 = __builtin_amdgcn_mfma_f32_32x32x16_bf16(gf0, pf.v, acc0, 0, 0, 0);
            acc1 = __builtin_amdgcn_mfma_f32_32x32x16_bf16(gf1, pf.v, acc1, 0, 0, 0);
        }
        __builtin_amdgcn_s_setprio(0);
        // next-iter phi prefetch (2 vmem ops, newest; left in flight across
        // the counted barrier below)
        int t0n = tbase + (((tc + 1) & 7) << 6);
        ph0 = *(const bf16x8*)&phiB[(t0n + sl) * 16 + hi * 8];
        ph1 = *(const bf16x8*)&phiB[(t0n + 32 + sl) * 16 + hi * 8];
#pragma unroll
        for (int i = 0; i < 8; ++i) {
            float e2 = __expf(sb[2 * i]);
            float e3 = __expf(sb[2 * i + 1]);
            lp4[2] += e2; lp4[3] += e3;
            u1[i] = cvtpk_bf16(e2, e3);
        }
        pl32swap(u1[0], u1[2]); pl32swap(u1[1], u1[3]);
        pl32swap(u1[4], u1[6]); pl32swap(u1[5], u1[7]);
        __builtin_amdgcn_s_setprio(1);
        {
            int co = (2 * 16 + hi * 8) ^ rsw;
            bf16x8 gf0 = *(const bf16x8*)&glr[sl * 64 + co];
            bf16x8 gf1 = *(const bf16x8*)&glr[(32 + sl) * 64 + co];
            union { unsigned w[4]; bf16x8 v; } pf = {{u1[0], u1[1], u1[2], u1[3]}};
            acc0 = __builtin_amdgcn_mfma_f32_32x32x16_bf16(gf0, pf.v, acc0, 0, 0, 0);
            acc1 = __builtin_amdgcn_mfma_f32_32x32x16_bf16(gf1, pf.v, acc1, 0, 0, 0);
        }
        {
            int co = (3 * 16 + hi * 8) ^ rsw;
            bf16x8 gf0 = *(const bf16x8*)&glr[sl * 64 + co];
            bf16x8 gf1 = *(const bf16x8*)&glr[(32 + sl) * 64 + co];
            union { unsigned w[4]; bf16x8 v; } pf = {{u1[4], u1[5], u1[6], u1[7]}};
            acc0 = __builtin_amdgcn_mfma_f32_32x32x16_bf16(gf0, pf.v, acc0, 0, 0, 0);
            acc1 = __builtin_amdgcn_mfma_f32_32x32x16_bf16(gf1, pf.v, acc1, 0, 0, 0);
        }
        __builtin_amdgcn_s_setprio(0);
        // counted-vmcnt barrier (T4): outstanding here = 4 DMA (older) +
        // 2 phi (newer). vmcnt(2) -> DMA landed; phi stays in flight.
        // sched_barrier(0) fences pin the issue order around the asm.
        if (tc < 7) {
            __builtin_amdgcn_sched_barrier(0);
            asm volatile("s_waitcnt vmcnt(2)" ::: "memory");
            __builtin_amdgcn_s_barrier();
            __builtin_amdgcn_sched_barrier(0);
        }
    }
    __syncthreads();   // all PV reads done before gl is reused as ldsOf

    // per-lane partial denominator (s = sl): reduce own 4 + partner half
    float tot = (lp4[0] + lp4[1]) + (lp4[2] + lp4[3]);
    tot += __shfl_xor(tot, 32);

    // cross-split exchange via LDS: both sp halves write partials, both
    // combine (each wave ends with the full normalized O words).
#pragma unroll
    for (int i = 0; i < 16; ++i) {
        int c = (i & 3) + 8 * (i >> 2) + 4 * hi;
        ldsOf[(sg * 2 + sp) * 2048 + c * 32 + sl] = acc0[i];
        ldsOf[(sg * 2 + sp) * 2048 + (32 + c) * 32 + sl] = acc1[i];
    }
    if (hi == 0) ldsD[sg][sp][sl] = tot;
    bf16x8 aw[2][4];
#pragma unroll
    for (int mt = 0; mt < 2; ++mt)
#pragma unroll
        for (int ch = 0; ch < 4; ++ch)
            aw[mt][ch] = *(const bf16x8*)&wo[(sp * 64 + mt * 32 + sl) * 64 + ch * 16 + hi * 8];
    __syncthreads();
    int osp = sp ^ 1;
    tot += ldsD[sg][osp][sl];
    float inv = 1.0f / tot;
#pragma unroll
    for (int i = 0; i < 16; ++i) {
        int c = (i & 3) + 8 * (i >> 2) + 4 * hi;
        acc0[i] += ldsOf[(sg * 2 + osp) * 2048 + c * 32 + sl];
        acc1[i] += ldsOf[(sg * 2 + osp) * 2048 + (32 + c) * 32 + sl];
    }
    // normalized O -> bf16 B-frags of out = Wo @ O (verified rounds 2-8)
    unsigned o0[8], o1[8];
#pragma unroll
    for (int i = 0; i < 8; ++i) {
        o0[i] = cvtpk_bf16(acc0[2 * i] * inv, acc0[2 * i + 1] * inv);
        o1[i] = cvtpk_bf16(acc1[2 * i] * inv, acc1[2 * i + 1] * inv);
    }
    pl32swap(o0[0], o0[2]); pl32swap(o0[1], o0[3]);
    pl32swap(o0[4], o0[6]); pl32swap(o0[5], o0[7]);
    pl32swap(o1[0], o1[2]); pl32swap(o1[1], o1[3]);
    pl32swap(o1[4], o1[6]); pl32swap(o1[5], o1[7]);
    bf16x8 bfr[4];
    {
        union { unsigned w[4]; bf16x8 v; } t;
        t.w[0] = o0[0]; t.w[1] = o0[1]; t.w[2] = o0[2]; t.w[3] = o0[3]; bfr[0] = t.v;
        t.w[0] = o0[4]; t.w[1] = o0[5]; t.w[2] = o0[6]; t.w[3] = o0[7]; bfr[1] = t.v;
        t.w[0] = o1[0]; t.w[1] = o1[1]; t.w[2] = o1[2]; t.w[3] = o1[3]; bfr[2] = t.v;
        t.w[0] = o1[4]; t.w[1] = o1[5]; t.w[2] = o1[6]; t.w[3] = o1[7]; bfr[3] = t.v;
    }
    // out = Wo @ O for this wave's 64 oc rows (2 m-tiles of 32)
    f32x16 d0 = z16, d1 = z16;
#pragma unroll
    for (int ch = 0; ch < 4; ++ch) {
        d0 = __builtin_amdgcn_mfma_f32_32x32x16_bf16(aw[0][ch], bfr[ch], d0, 0, 0, 0);
        d1 = __builtin_amdgcn_mfma_f32_32x32x16_bf16(aw[1][ch], bfr[ch], d1, 0, 0, 0);
    }
    // write gamma*D + x, non-temporal (no L2 pollution / RFO)
    float gm = gam[0];
    int scol = s0 + sg * 32 + sl;
#pragma unroll
    for (int i = 0; i < 16; ++i) {
        int r = (i & 3) + 8 * (i >> 2) + 4 * hi;
        int a0 = (bb * 128 + sp * 64 + r) * 4096 + scol;
        int a1 = (bb * 128 + sp * 64 + 32 + r) * 4096 + scol;
        float xv0 = __builtin_nontemporal_load(&x[a0]);
        float xv1 = __builtin_nontemporal_load(&x[a1]);
        __builtin_nontemporal_store(gm * d0[i] + xv0, &out[a0]);
        __builtin_nontemporal_store(gm * d1[i] + xv1, &out[a1]);
    }
}

extern "C" void kernel_launch(void* const* d_in, const int* in_sizes, int n_in,
                              void* d_out, int out_size, void* d_ws, size_t ws_size,
                              hipStream_t stream) {
    const float* x  = (const float*)d_in[0];
    const float* wt = (const float*)d_in[1];
    const float* wp = (const float*)d_in[2];
    const float* wg = (const float*)d_in[3];
    const float* wo = (const float*)d_in[4];
    const float* ut = (const float*)d_in[5];
    const float* up = (const float*)d_in[6];
    const float* ug = (const float*)d_in[7];
    const float* uo = (const float*)d_in[8];
    const float* gm = (const float*)d_in[9];
    unsigned short* wsu = (unsigned short*)d_ws;
    float* out = (float*)d_out;

    sn4<<<4, 256, 0, stream>>>(wt, wp, wg, wo, ut, up, ug, uo, wsu);
    convpool_mfma<<<512, 512, 0, stream>>>(x, wsu + U_WN,
                                           wsu + U_TH, wsu + U_PHI, wsu + U_G);
    attn_out<<<1024, 256, 0, stream>>>(wsu + U_TH, wsu + U_PHI, wsu + U_G,
                                       wsu + U_WO, x, gm, out);
}